// Round 6
// baseline (45.201 us; speedup 1.0000x reference)
//
#include <hip/hip_runtime.h>

#define BB 4
#define CC 512    // C_CTX
#define TDIM 512  // T
#define HH 128
#define TT 8      // t-rows per tile
#define CH 256    // c-half per score block
#define NSPLIT 2  // c-splits per (b, t-tile)

// ---------------- prep: key/query/value projections (f32 to ws) -------------
__global__ __launch_bounds__(128) void prep_kernel(
    const float* __restrict__ ctx_x, const float* __restrict__ ctx_y,
    const float* __restrict__ tgt_x,
    const float* __restrict__ W_in, const float* __restrict__ b_in,
    const float* __restrict__ W_ctx, const float* __restrict__ b_ctx,
    float* __restrict__ key, float* __restrict__ query, float* __restrict__ value)
{
    int row = blockIdx.x;     // b*512 + r
    int h   = threadIdx.x;    // 0..127

    float4 cx = ((const float4*)ctx_x)[row];
    float2 cy = ((const float2*)ctx_y)[row];
    float4 tx = ((const float4*)tgt_x)[row];

    float wi0 = W_in[0*HH+h], wi1 = W_in[1*HH+h], wi2 = W_in[2*HH+h];
    float wi3 = W_in[3*HH+h], wi4 = W_in[4*HH+h];
    float wc0 = W_ctx[0*HH+h], wc1 = W_ctx[1*HH+h], wc2 = W_ctx[2*HH+h];
    float bi  = b_in[h], bc = b_ctx[h];

    value[row*HH+h] = fmaf(cx.x,wi0, fmaf(cx.y,wi1, fmaf(cx.z,wi2, fmaf(cy.x,wi3, fmaf(cy.y,wi4, bi)))));
    key  [row*HH+h] = fmaf(cx.x,wc0, fmaf(cx.y,wc1, fmaf(cx.z,wc2, bc)));
    query[row*HH+h] = fmaf(tx.x,wc0, fmaf(tx.y,wc1, fmaf(tx.z,wc2, bc)));
}

// ------ main: scores + local softmax + PV partial + PROJ partial (per c-half)
// grid = 512 blocks, 256 threads, 52 KB LDS (~3 blocks/CU). Writes the
// PROJECTED unnormalized partial pp_j = repp_j @ W_tgt (linear, so it commutes
// with the flash combine), so the final combine is pure elementwise.
__global__ __launch_bounds__(256) void score_pv_kernel(
    const float* __restrict__ key, const float* __restrict__ query,
    const float* __restrict__ value, const float* __restrict__ W_tgt,
    float* __restrict__ pp, float* __restrict__ ml)
{
    const int bx   = blockIdx.x;          // b*128 + tb*2 + half
    const int b    = bx >> 7;
    const int tb   = (bx >> 1) & 63;
    const int half = bx & 1;
    const int t0   = tb * TT;
    const int c0   = half * CH;
    const int tid  = threadIdx.x;

    __shared__ float q[TT][HH];             // 4 KB; becomes rep[] after PV
    __shared__ float s[TT][CH];             // 8 KB raw scores
    __shared__ float pT[CH][TT];            // 8 KB unnormalized exp, transposed
    __shared__ float partial[8][TT][HH];    // 32 KB PV partials

    // --- q tile to LDS ---
    for (int i = tid; i < TT*HH; i += 256)
        q[i>>7][i&127] = query[(b*TDIM + t0 + (i>>7))*HH + (i&127)];
    __syncthreads();

    // --- scores: thread = (c-quad cq, h-quad hq). 4 k-rows live; each q
    //     float4 LDS read amortized over 4 c-rows. ---
    {
        const int cq = tid >> 2;   // 0..63 -> rows c0+cq*4 .. +3
        const int hq = tid & 3;    // 0..3  -> h-slice j*16 + hq*4
        const float* kp = &key[(b*CC + c0 + cq*4)*HH];
        float a0[TT], a1[TT], a2[TT], a3[TT];
        #pragma unroll
        for (int t = 0; t < TT; ++t) { a0[t]=0.f; a1[t]=0.f; a2[t]=0.f; a3[t]=0.f; }
        #pragma unroll
        for (int j = 0; j < 8; ++j) {
            const int hb = j*16 + hq*4;
            float4 k0 = *(const float4*)(kp + 0*HH + hb);
            float4 k1 = *(const float4*)(kp + 1*HH + hb);
            float4 k2 = *(const float4*)(kp + 2*HH + hb);
            float4 k3 = *(const float4*)(kp + 3*HH + hb);
            #pragma unroll
            for (int t = 0; t < TT; ++t) {
                float4 qv = *(const float4*)&q[t][hb];
                a0[t] += fabsf(k0.x-qv.x)+fabsf(k0.y-qv.y)+fabsf(k0.z-qv.z)+fabsf(k0.w-qv.w);
                a1[t] += fabsf(k1.x-qv.x)+fabsf(k1.y-qv.y)+fabsf(k1.z-qv.z)+fabsf(k1.w-qv.w);
                a2[t] += fabsf(k2.x-qv.x)+fabsf(k2.y-qv.y)+fabsf(k2.z-qv.z)+fabsf(k2.w-qv.w);
                a3[t] += fabsf(k3.x-qv.x)+fabsf(k3.y-qv.y)+fabsf(k3.z-qv.z)+fabsf(k3.w-qv.w);
            }
        }
        #pragma unroll
        for (int t = 0; t < TT; ++t) {
            float v0=a0[t], v1=a1[t], v2=a2[t], v3=a3[t];
            v0 += __shfl_xor(v0,1); v0 += __shfl_xor(v0,2);
            v1 += __shfl_xor(v1,1); v1 += __shfl_xor(v1,2);
            v2 += __shfl_xor(v2,1); v2 += __shfl_xor(v2,2);
            v3 += __shfl_xor(v3,1); v3 += __shfl_xor(v3,2);
            if (hq == 0)
                *(float4*)&s[t][cq*4] =
                    make_float4(-0.5f*v0, -0.5f*v1, -0.5f*v2, -0.5f*v3);
        }
    }
    __syncthreads();

    // --- local softmax over this c-half (wave per 2 t-rows) ---
    {
        const int wave = tid >> 6, lane = tid & 63;
        #pragma unroll
        for (int tw = 0; tw < 2; ++tw) {
            const int t = wave*2 + tw;
            float x0 = s[t][lane], x1 = s[t][lane+64], x2 = s[t][lane+128], x3 = s[t][lane+192];
            float m = fmaxf(fmaxf(x0, x1), fmaxf(x2, x3));
            #pragma unroll
            for (int msk = 32; msk; msk >>= 1) m = fmaxf(m, __shfl_xor(m, msk));
            float e0 = __expf(x0-m), e1 = __expf(x1-m), e2 = __expf(x2-m), e3 = __expf(x3-m);
            float sum = e0 + e1 + e2 + e3;
            #pragma unroll
            for (int msk = 32; msk; msk >>= 1) sum += __shfl_xor(sum, msk);
            pT[lane    ][t] = e0;
            pT[lane+ 64][t] = e1;
            pT[lane+128][t] = e2;
            pT[lane+192][t] = e3;
            if (lane == 0) { ml[bx*16 + t] = m; ml[bx*16 + 8 + t] = sum; }
        }
    }
    __syncthreads();

    // --- PV partial: thread = (c-octant g, h-quad hs); float4 coalesced ---
    {
        const int g  = tid >> 5;   // 0..7 -> local c range g*32..+31
        const int hs = tid & 31;   // h = hs*4 .. +3
        float4 acc[TT];
        #pragma unroll
        for (int t = 0; t < TT; ++t) acc[t] = make_float4(0.f,0.f,0.f,0.f);
        const float* vp = &value[(b*CC + c0 + g*32)*HH + hs*4];
        #pragma unroll 4
        for (int c = 0; c < 32; ++c) {
            float4 vv = *(const float4*)(vp + c*HH);
            float4 p0 = *(const float4*)&pT[g*32 + c][0];
            float4 p1 = *(const float4*)&pT[g*32 + c][4];
            acc[0].x=fmaf(p0.x,vv.x,acc[0].x); acc[0].y=fmaf(p0.x,vv.y,acc[0].y);
            acc[0].z=fmaf(p0.x,vv.z,acc[0].z); acc[0].w=fmaf(p0.x,vv.w,acc[0].w);
            acc[1].x=fmaf(p0.y,vv.x,acc[1].x); acc[1].y=fmaf(p0.y,vv.y,acc[1].y);
            acc[1].z=fmaf(p0.y,vv.z,acc[1].z); acc[1].w=fmaf(p0.y,vv.w,acc[1].w);
            acc[2].x=fmaf(p0.z,vv.x,acc[2].x); acc[2].y=fmaf(p0.z,vv.y,acc[2].y);
            acc[2].z=fmaf(p0.z,vv.z,acc[2].z); acc[2].w=fmaf(p0.z,vv.w,acc[2].w);
            acc[3].x=fmaf(p0.w,vv.x,acc[3].x); acc[3].y=fmaf(p0.w,vv.y,acc[3].y);
            acc[3].z=fmaf(p0.w,vv.z,acc[3].z); acc[3].w=fmaf(p0.w,vv.w,acc[3].w);
            acc[4].x=fmaf(p1.x,vv.x,acc[4].x); acc[4].y=fmaf(p1.x,vv.y,acc[4].y);
            acc[4].z=fmaf(p1.x,vv.z,acc[4].z); acc[4].w=fmaf(p1.x,vv.w,acc[4].w);
            acc[5].x=fmaf(p1.y,vv.x,acc[5].x); acc[5].y=fmaf(p1.y,vv.y,acc[5].y);
            acc[5].z=fmaf(p1.y,vv.z,acc[5].z); acc[5].w=fmaf(p1.y,vv.w,acc[5].w);
            acc[6].x=fmaf(p1.z,vv.x,acc[6].x); acc[6].y=fmaf(p1.z,vv.y,acc[6].y);
            acc[6].z=fmaf(p1.z,vv.z,acc[6].z); acc[6].w=fmaf(p1.z,vv.w,acc[6].w);
            acc[7].x=fmaf(p1.w,vv.x,acc[7].x); acc[7].y=fmaf(p1.w,vv.y,acc[7].y);
            acc[7].z=fmaf(p1.w,vv.z,acc[7].z); acc[7].w=fmaf(p1.w,vv.w,acc[7].w);
        }
        #pragma unroll
        for (int t = 0; t < TT; ++t)
            *(float4*)&partial[g][t][hs*4] = acc[t];
    }
    __syncthreads();

    // --- reduce 8 partials into rep (reuse q buffer; q is dead) ---
    for (int i = tid; i < TT*HH; i += 256) {
        float r = 0.f;
        #pragma unroll
        for (int g = 0; g < 8; ++g) r += partial[g][i>>7][i&127];
        q[i>>7][i&127] = r;
    }
    __syncthreads();

    // --- proj partial: pp_j[t][h] = rep_j[t][:] @ W_tgt[:][h] (no bias) ---
    {
        const int g = tid >> 7, h = tid & 127;   // g: t-quad
        float acc[4] = {0.f, 0.f, 0.f, 0.f};
        for (int k = 0; k < HH; k += 4) {
            float w0 = W_tgt[(k+0)*HH + h];
            float w1 = W_tgt[(k+1)*HH + h];
            float w2 = W_tgt[(k+2)*HH + h];
            float w3 = W_tgt[(k+3)*HH + h];
            #pragma unroll
            for (int i = 0; i < 4; ++i) {
                const float4 rv = *(const float4*)&q[g*4 + i][k];
                acc[i] = fmaf(rv.x, w0, fmaf(rv.y, w1, fmaf(rv.z, w2, fmaf(rv.w, w3, acc[i]))));
            }
        }
        #pragma unroll
        for (int i = 0; i < 4; ++i)
            pp[bx*(TT*HH) + (g*4 + i)*HH + h] = acc[i];
    }
}

// ------------- combine: out = cf0*pp0 + cf1*pp1 + b (pure elementwise) -------
__global__ __launch_bounds__(256) void combine_kernel(
    const float* __restrict__ pp, const float* __restrict__ ml,
    const float* __restrict__ b_tgt, float* __restrict__ out)
{
    const int bx   = blockIdx.x;       // 0..1023: tile = bx>>2, tp = bx&3
    const int tile = bx >> 2;          // b*64 + tb
    const int tp   = bx & 3;
    const int lt   = threadIdx.x >> 7; // 0..1 (uniform per wave-pair)
    const int h    = threadIdx.x & 127;
    const int t    = tp*2 + lt;        // 0..7 within tile

    const int blk0 = tile*2, blk1 = blk0 + 1;
    float m0 = ml[blk0*16 + t], l0 = ml[blk0*16 + 8 + t];
    float m1 = ml[blk1*16 + t], l1 = ml[blk1*16 + 8 + t];
    float M  = fmaxf(m0, m1);
    float a0 = __expf(m0 - M), a1 = __expf(m1 - M);
    float invL = 1.f / fmaf(a0, l0, a1 * l1);

    float p0 = pp[blk0*(TT*HH) + t*HH + h];
    float p1 = pp[blk1*(TT*HH) + t*HH + h];
    out[(tile*TT + t)*HH + h] = fmaf(a0*invL, p0, a1*invL*p1) + b_tgt[h];
}

extern "C" void kernel_launch(void* const* d_in, const int* in_sizes, int n_in,
                              void* d_out, int out_size, void* d_ws, size_t ws_size,
                              hipStream_t stream) {
    const float* ctx_x = (const float*)d_in[0];
    const float* ctx_y = (const float*)d_in[1];
    const float* tgt_x = (const float*)d_in[2];
    const float* W_in  = (const float*)d_in[3];
    const float* b_in  = (const float*)d_in[4];
    const float* W_ctx = (const float*)d_in[5];
    const float* b_ctx = (const float*)d_in[6];
    const float* W_tgt = (const float*)d_in[7];
    const float* b_tgt = (const float*)d_in[8];

    float* ws    = (float*)d_ws;
    float* key   = ws;                      // 262144 f32
    float* query = ws + 1*BB*CC*HH;         // 262144
    float* value = ws + 2*BB*CC*HH;         // 262144
    float* pp    = ws + 3*BB*CC*HH;         // 512 blocks * 1024
    float* ml    = pp + 512*TT*HH;          // 512 blocks * 16

    prep_kernel<<<BB*CC, 128, 0, stream>>>(ctx_x, ctx_y, tgt_x,
                                           W_in, b_in, W_ctx, b_ctx,
                                           key, query, value);
    score_pv_kernel<<<BB*(TDIM/TT)*NSPLIT, 256, 0, stream>>>(key, query, value,
                                                             W_tgt, pp, ml);
    combine_kernel<<<BB*(TDIM/TT)*4, 256, 0, stream>>>(pp, ml, b_tgt,
                                                       (float*)d_out);
}

// Round 7
// 44.685 us; speedup vs baseline: 1.0115x; 1.0115x over previous
//
#include <hip/hip_runtime.h>

#define BB 4
#define CC 512    // C_CTX
#define TDIM 512  // T
#define HH 128
#define TT 8      // t-rows per tile
#define CH 128    // c-quarter per score block
#define NSPLIT 4  // c-splits per (b, t-tile)

// ---------------- prep: key/query/value projections (f32 to ws) -------------
__global__ __launch_bounds__(128) void prep_kernel(
    const float* __restrict__ ctx_x, const float* __restrict__ ctx_y,
    const float* __restrict__ tgt_x,
    const float* __restrict__ W_in, const float* __restrict__ b_in,
    const float* __restrict__ W_ctx, const float* __restrict__ b_ctx,
    float* __restrict__ key, float* __restrict__ query, float* __restrict__ value)
{
    int row = blockIdx.x;     // b*512 + r
    int h   = threadIdx.x;    // 0..127

    float4 cx = ((const float4*)ctx_x)[row];
    float2 cy = ((const float2*)ctx_y)[row];
    float4 tx = ((const float4*)tgt_x)[row];

    float wi0 = W_in[0*HH+h], wi1 = W_in[1*HH+h], wi2 = W_in[2*HH+h];
    float wi3 = W_in[3*HH+h], wi4 = W_in[4*HH+h];
    float wc0 = W_ctx[0*HH+h], wc1 = W_ctx[1*HH+h], wc2 = W_ctx[2*HH+h];
    float bi  = b_in[h], bc = b_ctx[h];

    value[row*HH+h] = fmaf(cx.x,wi0, fmaf(cx.y,wi1, fmaf(cx.z,wi2, fmaf(cy.x,wi3, fmaf(cy.y,wi4, bi)))));
    key  [row*HH+h] = fmaf(cx.x,wc0, fmaf(cx.y,wc1, fmaf(cx.z,wc2, bc)));
    query[row*HH+h] = fmaf(tx.x,wc0, fmaf(tx.y,wc1, fmaf(tx.z,wc2, bc)));
}

// ------ main: scores + local softmax + PV partial, one c-quarter per block --
// grid = BB*(TDIM/TT)*NSPLIT = 1024 blocks (4/CU), 256 threads, 20 KB LDS.
__global__ __launch_bounds__(256) void score_pv_kernel(
    const float* __restrict__ key, const float* __restrict__ query,
    const float* __restrict__ value,
    float* __restrict__ repp, float* __restrict__ ml)
{
    const int bx      = blockIdx.x;        // tile*4 + quarter
    const int tile    = bx >> 2;           // b*64 + tb
    const int quarter = bx & 3;
    const int b       = tile >> 6;
    const int t0      = (tile & 63) * TT;
    const int c0      = quarter * CH;
    const int tid     = threadIdx.x;

    __shared__ float q[TT][HH];             // 4 KB
    __shared__ float s[TT][CH];             // 4 KB raw scores
    __shared__ float pT[CH][TT];            // 4 KB unnormalized exp, transposed
    __shared__ float partial[2][TT][HH];    // 8 KB PV partials

    // --- q tile to LDS ---
    for (int i = tid; i < TT*HH; i += 256)
        q[i>>7][i&127] = query[(b*TDIM + t0 + (i>>7))*HH + (i&127)];
    __syncthreads();

    // --- scores: thread = (c-quad cq, h-oct hq). 4 k-rows live; per load
    //     instr the 8 hq-lanes cover 128B of a row (full lines consumed).
    //     q float4 LDS reads are 8-address broadcast (conflict-free) and
    //     amortized over 4 c-rows. acc 4x8 + k 4x4 -> ~75 live VGPR.
    {
        const int cq = tid >> 3;   // 0..31 -> rows c0+cq*4 .. +3
        const int hq = tid & 7;    // 0..7  -> h-slice j*32 + hq*4, j=0..3
        const float* kp = &key[(b*CC + c0 + cq*4)*HH];
        float a0[TT], a1[TT], a2[TT], a3[TT];
        #pragma unroll
        for (int t = 0; t < TT; ++t) { a0[t]=0.f; a1[t]=0.f; a2[t]=0.f; a3[t]=0.f; }
        #pragma unroll
        for (int j = 0; j < 4; ++j) {
            const int hb = j*32 + hq*4;
            float4 k0 = *(const float4*)(kp + 0*HH + hb);
            float4 k1 = *(const float4*)(kp + 1*HH + hb);
            float4 k2 = *(const float4*)(kp + 2*HH + hb);
            float4 k3 = *(const float4*)(kp + 3*HH + hb);
            #pragma unroll
            for (int t = 0; t < TT; ++t) {
                float4 qv = *(const float4*)&q[t][hb];
                a0[t] += fabsf(k0.x-qv.x)+fabsf(k0.y-qv.y)+fabsf(k0.z-qv.z)+fabsf(k0.w-qv.w);
                a1[t] += fabsf(k1.x-qv.x)+fabsf(k1.y-qv.y)+fabsf(k1.z-qv.z)+fabsf(k1.w-qv.w);
                a2[t] += fabsf(k2.x-qv.x)+fabsf(k2.y-qv.y)+fabsf(k2.z-qv.z)+fabsf(k2.w-qv.w);
                a3[t] += fabsf(k3.x-qv.x)+fabsf(k3.y-qv.y)+fabsf(k3.z-qv.z)+fabsf(k3.w-qv.w);
            }
        }
        #pragma unroll
        for (int t = 0; t < TT; ++t) {
            float v0=a0[t], v1=a1[t], v2=a2[t], v3=a3[t];
            v0 += __shfl_xor(v0,1); v0 += __shfl_xor(v0,2); v0 += __shfl_xor(v0,4);
            v1 += __shfl_xor(v1,1); v1 += __shfl_xor(v1,2); v1 += __shfl_xor(v1,4);
            v2 += __shfl_xor(v2,1); v2 += __shfl_xor(v2,2); v2 += __shfl_xor(v2,4);
            v3 += __shfl_xor(v3,1); v3 += __shfl_xor(v3,2); v3 += __shfl_xor(v3,4);
            if (hq == 0)
                *(float4*)&s[t][cq*4] =
                    make_float4(-0.5f*v0, -0.5f*v1, -0.5f*v2, -0.5f*v3);
        }
    }
    __syncthreads();

    // --- local softmax over this c-quarter (wave per 2 t-rows) ---
    {
        const int wave = tid >> 6, lane = tid & 63;
        #pragma unroll
        for (int tw = 0; tw < 2; ++tw) {
            const int t = wave*2 + tw;
            float x0 = s[t][lane], x1 = s[t][lane+64];
            float m = fmaxf(x0, x1);
            #pragma unroll
            for (int msk = 32; msk; msk >>= 1) m = fmaxf(m, __shfl_xor(m, msk));
            float e0 = __expf(x0-m), e1 = __expf(x1-m);
            float sum = e0 + e1;
            #pragma unroll
            for (int msk = 32; msk; msk >>= 1) sum += __shfl_xor(sum, msk);
            pT[lane   ][t] = e0;
            pT[lane+64][t] = e1;
            if (lane == 0) { ml[bx*16 + t] = m; ml[bx*16 + 8 + t] = sum; }
        }
    }
    __syncthreads();

    // --- PV partial: thread = (c-group g, h). v loads coalesced 256B/wave;
    //     pT reads are wave-broadcast float4. ---
    {
        const int g = tid >> 7, h = tid & 127;    // g: 64 c-rows each
        float r[TT];
        #pragma unroll
        for (int t = 0; t < TT; ++t) r[t] = 0.f;
        const float* vp = &value[(b*CC + c0 + g*64)*HH + h];
        #pragma unroll 4
        for (int c = 0; c < 64; ++c) {
            float v = vp[c*HH];
            float4 p0 = *(const float4*)&pT[g*64 + c][0];
            float4 p1 = *(const float4*)&pT[g*64 + c][4];
            r[0] = fmaf(p0.x, v, r[0]);
            r[1] = fmaf(p0.y, v, r[1]);
            r[2] = fmaf(p0.z, v, r[2]);
            r[3] = fmaf(p0.w, v, r[3]);
            r[4] = fmaf(p1.x, v, r[4]);
            r[5] = fmaf(p1.y, v, r[5]);
            r[6] = fmaf(p1.z, v, r[6]);
            r[7] = fmaf(p1.w, v, r[7]);
        }
        #pragma unroll
        for (int t = 0; t < TT; ++t) partial[g][t][h] = r[t];
    }
    __syncthreads();

    // --- reduce 2 partials, write block result ---
    {
        const float* p0 = &partial[0][0][0];
        const float* p1 = &partial[1][0][0];
        for (int i = tid; i < TT*HH; i += 256)
            repp[bx*(TT*HH) + i] = p0[i] + p1[i];
    }
}

// ------------- combine 4 quarters + output projection ------------------------
// grid = 1024 blocks: one per (tile, t-pair). 256 thr = (lt = t within pair, h).
__global__ __launch_bounds__(256) void combine_proj_kernel(
    const float* __restrict__ repp, const float* __restrict__ ml,
    const float* __restrict__ W_tgt, const float* __restrict__ b_tgt,
    float* __restrict__ out)
{
    const int bx   = blockIdx.x;          // tile*4 + tp
    const int tile = bx >> 2;             // b*64 + tb
    const int tp   = bx & 3;
    const int lt   = threadIdx.x >> 7;    // 0..1 (uniform per wave)
    const int h    = threadIdx.x & 127;
    const int t    = tp*2 + lt;           // 0..7 within tile

    __shared__ float rep[2][HH];          // 1 KB

    float m[NSPLIT], l[NSPLIT], a[NSPLIT];
    float M = -1e30f;
    #pragma unroll
    for (int j = 0; j < NSPLIT; ++j) {
        m[j] = ml[(tile*NSPLIT + j)*16 + t];
        l[j] = ml[(tile*NSPLIT + j)*16 + 8 + t];
        M = fmaxf(M, m[j]);
    }
    float L = 0.f;
    #pragma unroll
    for (int j = 0; j < NSPLIT; ++j) { a[j] = __expf(m[j]-M); L = fmaf(a[j], l[j], L); }
    float invL = 1.f / L;

    float r = 0.f;
    #pragma unroll
    for (int j = 0; j < NSPLIT; ++j)
        r = fmaf(a[j]*invL, repp[(tile*NSPLIT + j)*(TT*HH) + t*HH + h], r);
    rep[lt][h] = r;
    __syncthreads();

    // proj: out[t][h] = rep[t][:] @ W_tgt[:][h] + b_tgt[h]
    float acc = b_tgt[h];
    const float* rl = &rep[lt][0];        // wave-uniform broadcast reads
    #pragma unroll 8
    for (int k = 0; k < HH; ++k)
        acc = fmaf(rl[k], W_tgt[k*HH + h], acc);

    out[(tile*TT + t)*HH + h] = acc;
}

extern "C" void kernel_launch(void* const* d_in, const int* in_sizes, int n_in,
                              void* d_out, int out_size, void* d_ws, size_t ws_size,
                              hipStream_t stream) {
    const float* ctx_x = (const float*)d_in[0];
    const float* ctx_y = (const float*)d_in[1];
    const float* tgt_x = (const float*)d_in[2];
    const float* W_in  = (const float*)d_in[3];
    const float* b_in  = (const float*)d_in[4];
    const float* W_ctx = (const float*)d_in[5];
    const float* b_ctx = (const float*)d_in[6];
    const float* W_tgt = (const float*)d_in[7];
    const float* b_tgt = (const float*)d_in[8];

    float* ws    = (float*)d_ws;
    float* key   = ws;                      // 262144 f32
    float* query = ws + 1*BB*CC*HH;         // 262144
    float* value = ws + 2*BB*CC*HH;         // 262144
    float* repp  = ws + 3*BB*CC*HH;         // 1024 blocks * 1024
    float* ml    = repp + 1024*TT*HH;       // 1024 blocks * 16

    prep_kernel<<<BB*CC, 128, 0, stream>>>(ctx_x, ctx_y, tgt_x,
                                           W_in, b_in, W_ctx, b_ctx,
                                           key, query, value);
    score_pv_kernel<<<BB*(TDIM/TT)*NSPLIT, 256, 0, stream>>>(key, query, value,
                                                             repp, ml);
    combine_proj_kernel<<<BB*(TDIM/TT)*NSPLIT, 256, 0, stream>>>(repp, ml, W_tgt,
                                                                 b_tgt, (float*)d_out);
}

// Round 8
// 41.792 us; speedup vs baseline: 1.0816x; 1.0692x over previous
//
#include <hip/hip_runtime.h>

#define BB 4
#define CC 512    // C_CTX
#define TDIM 512  // T
#define HH 128
#define TT 4      // t-rows per block
#define CHK 128   // c-rows per chunk
#define NCHK 4    // chunks (CC / CHK)

// ---------------- prep: key/query/value projections (f32 to ws) -------------
__global__ __launch_bounds__(128) void prep_kernel(
    const float* __restrict__ ctx_x, const float* __restrict__ ctx_y,
    const float* __restrict__ tgt_x,
    const float* __restrict__ W_in, const float* __restrict__ b_in,
    const float* __restrict__ W_ctx, const float* __restrict__ b_ctx,
    float* __restrict__ key, float* __restrict__ query, float* __restrict__ value)
{
    int row = blockIdx.x;     // b*512 + r
    int h   = threadIdx.x;    // 0..127

    float4 cx = ((const float4*)ctx_x)[row];
    float2 cy = ((const float2*)ctx_y)[row];
    float4 tx = ((const float4*)tgt_x)[row];

    float wi0 = W_in[0*HH+h], wi1 = W_in[1*HH+h], wi2 = W_in[2*HH+h];
    float wi3 = W_in[3*HH+h], wi4 = W_in[4*HH+h];
    float wc0 = W_ctx[0*HH+h], wc1 = W_ctx[1*HH+h], wc2 = W_ctx[2*HH+h];
    float bi  = b_in[h], bc = b_ctx[h];

    value[row*HH+h] = fmaf(cx.x,wi0, fmaf(cx.y,wi1, fmaf(cx.z,wi2, fmaf(cy.x,wi3, fmaf(cy.y,wi4, bi)))));
    key  [row*HH+h] = fmaf(cx.x,wc0, fmaf(cx.y,wc1, fmaf(cx.z,wc2, bc)));
    query[row*HH+h] = fmaf(tx.x,wc0, fmaf(tx.y,wc1, fmaf(tx.z,wc2, bc)));
}

// ---------- fused: flash over c-chunks: score -> online softmax -> PV (reg
// accumulators, rescaled per chunk) -> final reduce + projection.
// grid = BB*(TDIM/TT) = 512 blocks, 256 threads (4 waves), ~16 KB LDS.
__global__ __launch_bounds__(256) void fused_kernel(
    const float* __restrict__ key, const float* __restrict__ query,
    const float* __restrict__ value, const float* __restrict__ W_tgt,
    const float* __restrict__ b_tgt, float* __restrict__ out)
{
    const int bx  = blockIdx.x;          // b*128 + t-quad
    const int b   = bx >> 7;
    const int t0  = (bx & 127) * TT;
    const int tid = threadIdx.x;

    __shared__ __align__(16) float q[TT][HH];          // 2 KB; becomes rep[] at end
    __shared__ __align__(16) float s[TT][CHK];         // 2 KB raw scores
    __shared__ __align__(16) float pT[CHK][TT];        // 2 KB unnorm. exp, transposed
    __shared__ __align__(16) float fct[TT];            // per-chunk rescale factor
    __shared__ __align__(16) float linv[TT];           // final 1/l
    __shared__ __align__(16) float partial[4][TT][HH]; // 8 KB PV partials (end only)

    // --- q tile to LDS ---
    for (int i = tid; i < TT*HH; i += 256)
        q[i>>7][i&127] = query[(b*TDIM + t0 + (i>>7))*HH + (i&127)];

    // persistent per-thread state
    const int g  = tid >> 6;     // wave index 0..3 (= softmax t-row, = PV c-group)
    const int hp = tid & 63;     // h-pair index (h = 2*hp)
    float2 acc0 = {0.f,0.f}, acc1 = {0.f,0.f}, acc2 = {0.f,0.f}, acc3 = {0.f,0.f};
    float m_run = -1e30f, l_run = 0.f;   // wave-uniform online-softmax state (t = g)

    __syncthreads();

    for (int ch = 0; ch < NCHK; ++ch) {
        const int c0 = ch * CHK;

        // ---- scores: thread = (c-quad cq, h-oct hq). 4 k-rows live, q b128
        //      broadcasts amortized over 4 c-rows. ----
        {
            const int cq = tid >> 3;          // 0..31
            const int hq = tid & 7;           // 0..7
            const float* kp = &key[(b*CC + c0 + cq*4)*HH];
            float a0[TT], a1[TT], a2[TT], a3[TT];
            #pragma unroll
            for (int t = 0; t < TT; ++t) { a0[t]=0.f; a1[t]=0.f; a2[t]=0.f; a3[t]=0.f; }
            #pragma unroll
            for (int j = 0; j < 4; ++j) {
                const int hb = j*32 + hq*4;
                float4 k0 = *(const float4*)(kp + 0*HH + hb);
                float4 k1 = *(const float4*)(kp + 1*HH + hb);
                float4 k2 = *(const float4*)(kp + 2*HH + hb);
                float4 k3 = *(const float4*)(kp + 3*HH + hb);
                #pragma unroll
                for (int t = 0; t < TT; ++t) {
                    float4 qv = *(const float4*)&q[t][hb];
                    a0[t] += fabsf(k0.x-qv.x)+fabsf(k0.y-qv.y)+fabsf(k0.z-qv.z)+fabsf(k0.w-qv.w);
                    a1[t] += fabsf(k1.x-qv.x)+fabsf(k1.y-qv.y)+fabsf(k1.z-qv.z)+fabsf(k1.w-qv.w);
                    a2[t] += fabsf(k2.x-qv.x)+fabsf(k2.y-qv.y)+fabsf(k2.z-qv.z)+fabsf(k2.w-qv.w);
                    a3[t] += fabsf(k3.x-qv.x)+fabsf(k3.y-qv.y)+fabsf(k3.z-qv.z)+fabsf(k3.w-qv.w);
                }
            }
            #pragma unroll
            for (int t = 0; t < TT; ++t) {
                float v0=a0[t], v1=a1[t], v2=a2[t], v3=a3[t];
                v0 += __shfl_xor(v0,1); v0 += __shfl_xor(v0,2); v0 += __shfl_xor(v0,4);
                v1 += __shfl_xor(v1,1); v1 += __shfl_xor(v1,2); v1 += __shfl_xor(v1,4);
                v2 += __shfl_xor(v2,1); v2 += __shfl_xor(v2,2); v2 += __shfl_xor(v2,4);
                v3 += __shfl_xor(v3,1); v3 += __shfl_xor(v3,2); v3 += __shfl_xor(v3,4);
                if (hq == 0)
                    *(float4*)&s[t][cq*4] =
                        make_float4(-0.5f*v0, -0.5f*v1, -0.5f*v2, -0.5f*v3);
            }
        }
        __syncthreads();

        // ---- online softmax: wave g owns t-row g ----
        {
            const int lane = tid & 63;
            float x0 = s[g][lane], x1 = s[g][lane+64];
            float mc = fmaxf(x0, x1);
            #pragma unroll
            for (int msk = 32; msk; msk >>= 1) mc = fmaxf(mc, __shfl_xor(mc, msk));
            float m_new = fmaxf(m_run, mc);
            float e0 = __expf(x0 - m_new), e1 = __expf(x1 - m_new);
            float sum = e0 + e1;
            #pragma unroll
            for (int msk = 32; msk; msk >>= 1) sum += __shfl_xor(sum, msk);
            float f = __expf(m_run - m_new);
            l_run = fmaf(l_run, f, sum);
            m_run = m_new;
            pT[lane   ][g] = e0;
            pT[lane+64][g] = e1;
            if (lane == 0) fct[g] = f;
        }
        __syncthreads();

        // ---- PV: thread = (c-group g: 32 rows, h-pair hp). One b128 pT
        //      broadcast per c feeds 8 fma (4 t x 2 h). v loads coalesced. ----
        {
            const float4 fv = *(const float4*)&fct[0];
            acc0.x *= fv.x; acc0.y *= fv.x;
            acc1.x *= fv.y; acc1.y *= fv.y;
            acc2.x *= fv.z; acc2.y *= fv.z;
            acc3.x *= fv.w; acc3.y *= fv.w;
            const float* vp = &value[(b*CC + c0 + g*32)*HH + hp*2];
            #pragma unroll 4
            for (int c = 0; c < 32; ++c) {
                float2 vv = *(const float2*)(vp + c*HH);
                float4 p  = *(const float4*)&pT[g*32 + c][0];
                acc0.x = fmaf(p.x, vv.x, acc0.x); acc0.y = fmaf(p.x, vv.y, acc0.y);
                acc1.x = fmaf(p.y, vv.x, acc1.x); acc1.y = fmaf(p.y, vv.y, acc1.y);
                acc2.x = fmaf(p.z, vv.x, acc2.x); acc2.y = fmaf(p.z, vv.y, acc2.y);
                acc3.x = fmaf(p.w, vv.x, acc3.x); acc3.y = fmaf(p.w, vv.y, acc3.y);
            }
        }
        __syncthreads();
    }

    // ---- final: partials to LDS, reduce into rep (reuse q), normalize ----
    if ((tid & 63) == 0) linv[g] = 1.f / l_run;
    *(float2*)&partial[g][0][hp*2] = acc0;
    *(float2*)&partial[g][1][hp*2] = acc1;
    *(float2*)&partial[g][2][hp*2] = acc2;
    *(float2*)&partial[g][3][hp*2] = acc3;
    __syncthreads();
    for (int i = tid; i < TT*HH; i += 256) {
        const int t = i>>7, h = i&127;
        q[t][h] = (partial[0][t][h] + partial[1][t][h] +
                   partial[2][t][h] + partial[3][t][h]) * linv[t];
    }
    __syncthreads();

    // ---- projection: thread (lt, h) -> rows t0+lt, t0+lt+2 ----
    {
        const int lt = tid >> 7, h = tid & 127;
        float o0 = b_tgt[h], o1 = o0;
        for (int k = 0; k < HH; k += 4) {
            float4 r0 = *(const float4*)&q[lt    ][k];
            float4 r1 = *(const float4*)&q[lt + 2][k];
            float w0 = W_tgt[(k+0)*HH + h];
            float w1 = W_tgt[(k+1)*HH + h];
            float w2 = W_tgt[(k+2)*HH + h];
            float w3 = W_tgt[(k+3)*HH + h];
            o0 = fmaf(r0.x,w0, fmaf(r0.y,w1, fmaf(r0.z,w2, fmaf(r0.w,w3, o0))));
            o1 = fmaf(r1.x,w0, fmaf(r1.y,w1, fmaf(r1.z,w2, fmaf(r1.w,w3, o1))));
        }
        out[(b*TDIM + t0 + lt    )*HH + h] = o0;
        out[(b*TDIM + t0 + lt + 2)*HH + h] = o1;
    }
}

extern "C" void kernel_launch(void* const* d_in, const int* in_sizes, int n_in,
                              void* d_out, int out_size, void* d_ws, size_t ws_size,
                              hipStream_t stream) {
    const float* ctx_x = (const float*)d_in[0];
    const float* ctx_y = (const float*)d_in[1];
    const float* tgt_x = (const float*)d_in[2];
    const float* W_in  = (const float*)d_in[3];
    const float* b_in  = (const float*)d_in[4];
    const float* W_ctx = (const float*)d_in[5];
    const float* b_ctx = (const float*)d_in[6];
    const float* W_tgt = (const float*)d_in[7];
    const float* b_tgt = (const float*)d_in[8];

    float* ws    = (float*)d_ws;
    float* key   = ws;                      // 262144 f32
    float* query = ws + 1*BB*CC*HH;         // 262144
    float* value = ws + 2*BB*CC*HH;         // 262144

    prep_kernel<<<BB*CC, 128, 0, stream>>>(ctx_x, ctx_y, tgt_x,
                                           W_in, b_in, W_ctx, b_ctx,
                                           key, query, value);
    fused_kernel<<<BB*(TDIM/TT), 256, 0, stream>>>(key, query, value,
                                                   W_tgt, b_tgt, (float*)d_out);
}

// Round 9
// 35.984 us; speedup vs baseline: 1.2561x; 1.1614x over previous
//
#include <hip/hip_runtime.h>

#define BB 4
#define CC 512    // C_CTX
#define TDIM 512  // T
#define HH 128
#define TT 4      // t-rows per block
#define CHK 128   // c-rows per chunk
#define NCHK 4    // chunks

// ---------------- prep: key/query/value projections (f32 to ws) -------------
__global__ __launch_bounds__(128) void prep_kernel(
    const float* __restrict__ ctx_x, const float* __restrict__ ctx_y,
    const float* __restrict__ tgt_x,
    const float* __restrict__ W_in, const float* __restrict__ b_in,
    const float* __restrict__ W_ctx, const float* __restrict__ b_ctx,
    float* __restrict__ key, float* __restrict__ query, float* __restrict__ value)
{
    int row = blockIdx.x;     // b*512 + r
    int h   = threadIdx.x;    // 0..127

    float4 cx = ((const float4*)ctx_x)[row];
    float2 cy = ((const float2*)ctx_y)[row];
    float4 tx = ((const float4*)tgt_x)[row];

    float wi0 = W_in[0*HH+h], wi1 = W_in[1*HH+h], wi2 = W_in[2*HH+h];
    float wi3 = W_in[3*HH+h], wi4 = W_in[4*HH+h];
    float wc0 = W_ctx[0*HH+h], wc1 = W_ctx[1*HH+h], wc2 = W_ctx[2*HH+h];
    float bi  = b_in[h], bc = b_ctx[h];

    value[row*HH+h] = fmaf(cx.x,wi0, fmaf(cx.y,wi1, fmaf(cx.z,wi2, fmaf(cy.x,wi3, fmaf(cy.y,wi4, bi)))));
    key  [row*HH+h] = fmaf(cx.x,wc0, fmaf(cx.y,wc1, fmaf(cx.z,wc2, bc)));
    query[row*HH+h] = fmaf(tx.x,wc0, fmaf(tx.y,wc1, fmaf(tx.z,wc2, bc)));
}

// ---------- fused flash, software-pipelined: score(ch+1) co-resident with
// PV(ch) in the same barrier region (double-buffered s/pT) so VALU-heavy and
// LDS-heavy phases overlap across waves. q lives in registers (no LDS reads).
// grid = BB*(TDIM/TT) = 512 blocks, 256 threads, ~27 KB LDS.
__global__ __launch_bounds__(256) void fused_kernel(
    const float* __restrict__ key, const float* __restrict__ query,
    const float* __restrict__ value, const float* __restrict__ W_tgt,
    const float* __restrict__ b_tgt, float* __restrict__ out)
{
    const int bx   = blockIdx.x;          // b*128 + t-quad
    const int b    = bx >> 7;
    const int t0   = (bx & 127) * TT;
    const int tid  = threadIdx.x;
    const int g    = tid >> 6;            // wave 0..3 (= softmax t-row, PV c-group)
    const int lane = tid & 63;

    __shared__ __align__(16) float s[2][TT][CHK];      // 4 KB raw scores (dbuf)
    __shared__ __align__(16) float pT[2][CHK][TT];     // 4 KB exp, transposed (dbuf)
    __shared__ __align__(16) float fct[2][TT];         // rescale factors
    __shared__ __align__(16) float linv[TT];
    __shared__ __align__(16) float partial[8][TT][HH]; // 16 KB PV partials (end)
    __shared__ __align__(16) float rep[TT][HH];        // 2 KB

    // --- score role: (cq = c-quad, hq = h-slice). q held in 64 registers. ---
    const int cq = tid >> 3;   // 0..31
    const int hq = tid & 7;    // 0..7
    float4 qr[TT][4];
    #pragma unroll
    for (int t = 0; t < TT; ++t)
        #pragma unroll
        for (int j = 0; j < 4; ++j)
            qr[t][j] = *(const float4*)&query[(b*TDIM + t0 + t)*HH + j*32 + hq*4];

    // --- PV role: wave g owns 32 c-rows; cs picks 16-row sub, hv the h-quad ---
    const int cs = lane >> 5;  // 0..1
    const int hv = lane & 31;  // h = hv*4
    float4 acc[TT];
    #pragma unroll
    for (int t = 0; t < TT; ++t) acc[t] = make_float4(0.f,0.f,0.f,0.f);
    float m_run = -1e30f, l_run = 0.f;   // wave-uniform (t = g)

    auto SCORE = [&](int ch, int p) {
        const float* kp = &key[(b*CC + ch*CHK + cq*4)*HH];
        float a0[TT], a1[TT], a2[TT], a3[TT];
        #pragma unroll
        for (int t = 0; t < TT; ++t) { a0[t]=0.f; a1[t]=0.f; a2[t]=0.f; a3[t]=0.f; }
        #pragma unroll
        for (int j = 0; j < 4; ++j) {
            const int hb = j*32 + hq*4;
            float4 k0 = *(const float4*)(kp + 0*HH + hb);
            float4 k1 = *(const float4*)(kp + 1*HH + hb);
            float4 k2 = *(const float4*)(kp + 2*HH + hb);
            float4 k3 = *(const float4*)(kp + 3*HH + hb);
            #pragma unroll
            for (int t = 0; t < TT; ++t) {
                float4 qv = qr[t][j];
                a0[t] += fabsf(k0.x-qv.x)+fabsf(k0.y-qv.y)+fabsf(k0.z-qv.z)+fabsf(k0.w-qv.w);
                a1[t] += fabsf(k1.x-qv.x)+fabsf(k1.y-qv.y)+fabsf(k1.z-qv.z)+fabsf(k1.w-qv.w);
                a2[t] += fabsf(k2.x-qv.x)+fabsf(k2.y-qv.y)+fabsf(k2.z-qv.z)+fabsf(k2.w-qv.w);
                a3[t] += fabsf(k3.x-qv.x)+fabsf(k3.y-qv.y)+fabsf(k3.z-qv.z)+fabsf(k3.w-qv.w);
            }
        }
        #pragma unroll
        for (int t = 0; t < TT; ++t) {
            float v0=a0[t], v1=a1[t], v2=a2[t], v3=a3[t];
            v0 += __shfl_xor(v0,1); v0 += __shfl_xor(v0,2); v0 += __shfl_xor(v0,4);
            v1 += __shfl_xor(v1,1); v1 += __shfl_xor(v1,2); v1 += __shfl_xor(v1,4);
            v2 += __shfl_xor(v2,1); v2 += __shfl_xor(v2,2); v2 += __shfl_xor(v2,4);
            v3 += __shfl_xor(v3,1); v3 += __shfl_xor(v3,2); v3 += __shfl_xor(v3,4);
            if (hq == 0)
                *(float4*)&s[p][t][cq*4] =
                    make_float4(-0.5f*v0, -0.5f*v1, -0.5f*v2, -0.5f*v3);
        }
    };

    auto SOFTMAX = [&](int p) {
        float x0 = s[p][g][lane], x1 = s[p][g][lane+64];
        float mc = fmaxf(x0, x1);
        #pragma unroll
        for (int msk = 32; msk; msk >>= 1) mc = fmaxf(mc, __shfl_xor(mc, msk));
        float m_new = fmaxf(m_run, mc);
        float e0 = __expf(x0 - m_new), e1 = __expf(x1 - m_new);
        float sum = e0 + e1;
        #pragma unroll
        for (int msk = 32; msk; msk >>= 1) sum += __shfl_xor(sum, msk);
        float f = __expf(m_run - m_new);
        l_run = fmaf(l_run, f, sum);
        m_run = m_new;
        pT[p][lane   ][g] = e0;
        pT[p][lane+64][g] = e1;
        if (lane == 0) fct[p][g] = f;
    };

    auto PV = [&](int ch, int p) {
        const float4 fv = *(const float4*)&fct[p][0];
        acc[0].x*=fv.x; acc[0].y*=fv.x; acc[0].z*=fv.x; acc[0].w*=fv.x;
        acc[1].x*=fv.y; acc[1].y*=fv.y; acc[1].z*=fv.y; acc[1].w*=fv.y;
        acc[2].x*=fv.z; acc[2].y*=fv.z; acc[2].z*=fv.z; acc[2].w*=fv.z;
        acc[3].x*=fv.w; acc[3].y*=fv.w; acc[3].z*=fv.w; acc[3].w*=fv.w;
        const int cbase = g*32 + cs*16;
        const float* vp = &value[(b*CC + ch*CHK + cbase)*HH + hv*4];
        #pragma unroll 4
        for (int c = 0; c < 16; ++c) {
            float4 p4 = *(const float4*)&pT[p][cbase + c][0];
            float4 vv = *(const float4*)(vp + c*HH);
            acc[0].x=fmaf(p4.x,vv.x,acc[0].x); acc[0].y=fmaf(p4.x,vv.y,acc[0].y);
            acc[0].z=fmaf(p4.x,vv.z,acc[0].z); acc[0].w=fmaf(p4.x,vv.w,acc[0].w);
            acc[1].x=fmaf(p4.y,vv.x,acc[1].x); acc[1].y=fmaf(p4.y,vv.y,acc[1].y);
            acc[1].z=fmaf(p4.y,vv.z,acc[1].z); acc[1].w=fmaf(p4.y,vv.w,acc[1].w);
            acc[2].x=fmaf(p4.z,vv.x,acc[2].x); acc[2].y=fmaf(p4.z,vv.y,acc[2].y);
            acc[2].z=fmaf(p4.z,vv.z,acc[2].z); acc[2].w=fmaf(p4.z,vv.w,acc[2].w);
            acc[3].x=fmaf(p4.w,vv.x,acc[3].x); acc[3].y=fmaf(p4.w,vv.y,acc[3].y);
            acc[3].z=fmaf(p4.w,vv.z,acc[3].z); acc[3].w=fmaf(p4.w,vv.w,acc[3].w);
        }
    };

    // ---- pipelined schedule: score(ch+1) ∥ PV(ch) in one region ----
    SCORE(0, 0);
    __syncthreads();
    SOFTMAX(0);
    __syncthreads();
    SCORE(1, 1);  PV(0, 0);
    __syncthreads();
    SOFTMAX(1);
    __syncthreads();
    SCORE(2, 0);  PV(1, 1);
    __syncthreads();
    SOFTMAX(0);
    __syncthreads();
    SCORE(3, 1);  PV(2, 0);
    __syncthreads();
    SOFTMAX(1);
    __syncthreads();
    PV(3, 1);

    // ---- final: partials -> reduce -> normalize -> projection ----
    if (lane == 0) linv[g] = 1.f / l_run;
    #pragma unroll
    for (int t = 0; t < TT; ++t)
        *(float4*)&partial[g*2 + cs][t][hv*4] = acc[t];
    __syncthreads();

    for (int i = tid; i < TT*HH; i += 256) {
        const int t = i >> 7, h = i & 127;
        float r = 0.f;
        #pragma unroll
        for (int gg = 0; gg < 8; ++gg) r += partial[gg][t][h];
        rep[t][h] = r * linv[t];
    }
    __syncthreads();

    {
        const int lt = tid >> 7, h = tid & 127;
        float o0 = b_tgt[h], o1 = o0;
        for (int k = 0; k < HH; k += 4) {
            float4 r0 = *(const float4*)&rep[lt    ][k];
            float4 r1 = *(const float4*)&rep[lt + 2][k];
            float w0 = W_tgt[(k+0)*HH + h];
            float w1 = W_tgt[(k+1)*HH + h];
            float w2 = W_tgt[(k+2)*HH + h];
            float w3 = W_tgt[(k+3)*HH + h];
            o0 = fmaf(r0.x,w0, fmaf(r0.y,w1, fmaf(r0.z,w2, fmaf(r0.w,w3, o0))));
            o1 = fmaf(r1.x,w0, fmaf(r1.y,w1, fmaf(r1.z,w2, fmaf(r1.w,w3, o1))));
        }
        out[(b*TDIM + t0 + lt    )*HH + h] = o0;
        out[(b*TDIM + t0 + lt + 2)*HH + h] = o1;
    }
}

extern "C" void kernel_launch(void* const* d_in, const int* in_sizes, int n_in,
                              void* d_out, int out_size, void* d_ws, size_t ws_size,
                              hipStream_t stream) {
    const float* ctx_x = (const float*)d_in[0];
    const float* ctx_y = (const float*)d_in[1];
    const float* tgt_x = (const float*)d_in[2];
    const float* W_in  = (const float*)d_in[3];
    const float* b_in  = (const float*)d_in[4];
    const float* W_ctx = (const float*)d_in[5];
    const float* b_ctx = (const float*)d_in[6];
    const float* W_tgt = (const float*)d_in[7];
    const float* b_tgt = (const float*)d_in[8];

    float* ws    = (float*)d_ws;
    float* key   = ws;                      // 262144 f32
    float* query = ws + 1*BB*CC*HH;         // 262144
    float* value = ws + 2*BB*CC*HH;         // 262144

    prep_kernel<<<BB*CC, 128, 0, stream>>>(ctx_x, ctx_y, tgt_x,
                                           W_in, b_in, W_ctx, b_ctx,
                                           key, query, value);
    fused_kernel<<<BB*(TDIM/TT), 256, 0, stream>>>(key, query, value,
                                                   W_tgt, b_tgt, (float*)d_out);
}